// Round 2
// baseline (1702.963 us; speedup 1.0000x reference)
//
#include <hip/hip_runtime.h>
#include <hip/hip_bf16.h>

// Problem: B=32, Q=16, F=4096, E=256, NL=8, L=2 residual layers per mapper.
#define B_   32
#define Q_   16
#define F_   4096
#define E_   256
#define NL_  8
#define LAY_ 2
#define FT   64     // feature rows per chunk
#define TPB  256    // 4 waves

typedef __attribute__((ext_vector_type(8))) __bf16 bf16x8_t;
typedef __attribute__((ext_vector_type(4))) __bf16 bf16x4_t;
typedef __attribute__((ext_vector_type(4))) float  f32x4;

// ---- LDS swizzle for the [64][256] bf16 tile (row stride 512 B) ----
__device__ __forceinline__ int swz(int r) {
  return ((r & 7) << 4) ^ (((r >> 3) & 3) << 5);
}
__device__ __forceinline__ int xoff(int r, int c2) {  // c2 = byte offset in row [0,512)
  return r * 512 + (c2 ^ swz(r));
}

__device__ __forceinline__ unsigned short f2bf_bits(float f) {
  __bf16 h = (__bf16)f;
  return __builtin_bit_cast(unsigned short, h);
}

// ---------------- kernel 0: weight prep (fp32 [l][k][n] -> bf16 [l][n][k]) ----
__global__ __launch_bounds__(256) void prep_kernel(
    const float* __restrict__ Wf, const float* __restrict__ Wv,
    unsigned short* __restrict__ WtF, unsigned short* __restrict__ WtV) {
  int idx = blockIdx.x * 256 + threadIdx.x;   // 4*65536 total
  int ml = idx >> 16;                         // 0,1: Wf layers; 2,3: Wv layers
  int r  = idx & 0xFFFF;
  int n  = r >> 8, k = r & 255;
  const float* src = (ml < 2) ? (Wf + ml * 65536) : (Wv + (ml - 2) * 65536);
  unsigned short* dst = (ml < 2) ? (WtF + ml * 65536) : (WtV + (ml - 2) * 65536);
  dst[n * 256 + k] = f2bf_bits(src[k * 256 + n]);
}

// ---------------- kernel 1: q mapper (fp32), store bf16 qm ------------------
__global__ __launch_bounds__(256) void qmap_kernel(
    const float* __restrict__ query, const float* __restrict__ Wq,
    const float* __restrict__ bq, unsigned short* __restrict__ qmb) {
  int b = blockIdx.x, t = threadIdx.x;
  __shared__ float xq[Q_][E_ + 1];
  for (int j = 0; j < Q_; ++j) xq[j][t] = query[(b * Q_ + j) * E_ + t];
  __syncthreads();
  for (int l = 0; l < LAY_; ++l) {
    const float* W = Wq + l * E_ * E_;
    float acc[Q_];
#pragma unroll
    for (int r = 0; r < Q_; ++r) acc[r] = 0.f;
    for (int k = 0; k < E_; ++k) {
      float wv = W[k * E_ + t];
#pragma unroll
      for (int r = 0; r < Q_; ++r) acc[r] += xq[r][k] * wv;
    }
    float be = bq[l * E_ + t];
    __syncthreads();
#pragma unroll
    for (int r = 0; r < Q_; ++r) xq[r][t] = fmaxf(acc[r] + be, 0.f) + xq[r][t];
    __syncthreads();
  }
  for (int j = 0; j < Q_; ++j) qmb[(b * Q_ + j) * E_ + t] = f2bf_bits(xq[j][t]);
}

// ---------------- staging: fp32 global tile -> bf16 swizzled LDS ------------
__device__ __forceinline__ void stage_tile(char* Xs, const float* __restrict__ src, int tid) {
#pragma unroll
  for (int j = 0; j < 8; ++j) {
    int u  = j * 256 + tid;        // 16B-unit index, 2048 units
    int r  = u >> 5;               // row
    int cb = (u & 31) << 4;        // byte in row
    const float4* s4 = (const float4*)(src + r * E_ + ((u & 31) << 3));
    float4 v0 = s4[0], v1 = s4[1];
    bf16x8_t t;
    t[0] = (__bf16)v0.x; t[1] = (__bf16)v0.y; t[2] = (__bf16)v0.z; t[3] = (__bf16)v0.w;
    t[4] = (__bf16)v1.x; t[5] = (__bf16)v1.y; t[6] = (__bf16)v1.z; t[7] = (__bf16)v1.w;
    *(bf16x8_t*)(Xs + xoff(r, cb)) = t;
  }
}

// ---- Swapped-orientation residual layer, in-place on the LDS tile ----------
// a-frag = W rows (e-dim, from global/L2), b-frag = X rows (m-dim, from LDS).
// D[e][m]: thread holds 4 CONSECUTIVE e at fixed m -> b64 residual RMW.
__device__ __forceinline__ void mapper_layer(char* Xs, const unsigned short* __restrict__ Wt,
                                             const float* __restrict__ bias, int w, int lane) {
  f32x4 acc[4][4];
#pragma unroll
  for (int ef = 0; ef < 4; ++ef)
#pragma unroll
    for (int mf = 0; mf < 4; ++mf) acc[ef][mf] = (f32x4){0.f, 0.f, 0.f, 0.f};
  const int c16 = lane & 15;
  const int g   = lane >> 4;
  const int kb  = g << 3;
#pragma unroll
  for (int ks = 0; ks < 8; ++ks) {
    const int k = ks * 32 + kb;
    bf16x8_t xb[4];
#pragma unroll
    for (int mf = 0; mf < 4; ++mf)
      xb[mf] = *(const bf16x8_t*)(Xs + xoff(mf * 16 + c16, k << 1));
#pragma unroll
    for (int ef = 0; ef < 4; ++ef) {
      const int e = w * 64 + ef * 16 + c16;
      bf16x8_t wa = *(const bf16x8_t*)(Wt + e * E_ + k);
#pragma unroll
      for (int mf = 0; mf < 4; ++mf)
        acc[ef][mf] = __builtin_amdgcn_mfma_f32_16x16x32_bf16(wa, xb[mf], acc[ef][mf], 0, 0, 0);
    }
  }
  __syncthreads();   // all waves' K-loop reads of Xs done before in-place update
#pragma unroll
  for (int ef = 0; ef < 4; ++ef) {
    const int e0 = w * 64 + ef * 16 + (g << 2);
    const float4 b4 = *(const float4*)(bias + e0);
#pragma unroll
    for (int mf = 0; mf < 4; ++mf) {
      const int m = mf * 16 + c16;
      bf16x4_t* p = (bf16x4_t*)(Xs + xoff(m, e0 << 1));
      bf16x4_t old = *p;
      bf16x4_t nw;
      nw[0] = (__bf16)(fmaxf(acc[ef][mf][0] + b4.x, 0.f) + (float)old[0]);
      nw[1] = (__bf16)(fmaxf(acc[ef][mf][1] + b4.y, 0.f) + (float)old[1]);
      nw[2] = (__bf16)(fmaxf(acc[ef][mf][2] + b4.z, 0.f) + (float)old[2]);
      nw[3] = (__bf16)(fmaxf(acc[ef][mf][3] + b4.w, 0.f) + (float)old[3]);
      *p = nw;
    }
  }
  __syncthreads();
}

__global__ __launch_bounds__(TPB, 4) void fused_kernel(
    const float* __restrict__ features, const float* __restrict__ values,
    const float* __restrict__ amask, const float* __restrict__ ftw,
    const unsigned short* __restrict__ WtF, const float* __restrict__ bfb,
    const unsigned short* __restrict__ WtV, const float* __restrict__ bvb,
    const unsigned short* __restrict__ qmb, float* __restrict__ partials,
    int nt, int ch) {
  const int bid = blockIdx.x;
  const int b = bid / nt, tb = bid % nt;
  const int tid = threadIdx.x;
  const int lane = tid & 63, w = tid >> 6;
  const int c16 = lane & 15;
  const int g   = lane >> 4;
  const int kb  = g << 3;

  __shared__ __align__(128) char Xs[FT * 512];            // 32 KB bf16 tile (swizzled)
  __shared__ __align__(16) unsigned short Ws[Q_][FT + 8]; // attn weights [q][f] bf16

  f32x4 pacc[4];
#pragma unroll
  for (int nf = 0; nf < 4; ++nf) pacc[nf] = (f32x4){0.f, 0.f, 0.f, 0.f};

  for (int c = 0; c < ch; ++c) {
    const int f0 = (tb * ch + c) * FT;

    // ---- features tile -> Xs, f-mapper (2 layers) ----
    stage_tile(Xs, features + (size_t)(b * F_ + f0) * E_, tid);
    __syncthreads();
    mapper_layer(Xs, WtF, bfb, w, lane);
    mapper_layer(Xs, WtF + 65536, bfb + E_, w, lane);

    // ---- S = qm @ Fm^T: a = qm rows (q), b = Fm rows (f). D[q][f-col]. ----
    {
      f32x4 s = (f32x4){0.f, 0.f, 0.f, 0.f};
      const int fl = w * 16 + c16;
      const unsigned short* qbase = qmb + (size_t)(b * Q_ + c16) * E_ + kb;
#pragma unroll
      for (int ks = 0; ks < 8; ++ks) {
        bf16x8_t qa = *(const bf16x8_t*)(qbase + ks * 32);
        bf16x8_t xb = *(const bf16x8_t*)(Xs + xoff(fl, (ks * 32 + kb) << 1));
        s = __builtin_amdgcn_mfma_f32_16x16x32_bf16(qa, xb, s, 0, 0, 0);
      }
      const int fg = f0 + fl;
      const float lw = ftw[b * F_ + fg] * amask[b * F_ + fg];
#pragma unroll
      for (int r = 0; r < 4; ++r) {
        float sg = 1.f / (1.f + __expf(-s[r]));
        Ws[g * 4 + r][fl] = f2bf_bits(sg * lw);
      }
    }
    __syncthreads();   // S reads Xs; Ws written — before V overwrites Xs

    // ---- values tile -> Xs, v-mapper (2 layers) ----
    stage_tile(Xs, values + (size_t)(b * F_ + f0) * E_, tid);
    __syncthreads();
    mapper_layer(Xs, WtV, bvb, w, lane);
    mapper_layer(Xs, WtV + 65536, bvb + E_, w, lane);

    // ---- P += Ws[16,FT] @ Vm[FT,256]: a = Ws rows (q), b = Vm^T gather ----
    {
#pragma unroll
      for (int ks = 0; ks < FT / 32; ++ks) {
        bf16x8_t a = *(const bf16x8_t*)&Ws[c16][ks * 32 + kb];
#pragma unroll
        for (int nf = 0; nf < 4; ++nf) {
          const int e = w * 64 + nf * 16 + c16;
          bf16x8_t bb;
#pragma unroll
          for (int i = 0; i < 8; ++i) {
            const int f = ks * 32 + kb + i;
            bb[i] = *(const __bf16*)(Xs + xoff(f, e << 1));
          }
          pacc[nf] = __builtin_amdgcn_mfma_f32_16x16x32_bf16(a, bb, pacc[nf], 0, 0, 0);
        }
      }
    }
    __syncthreads();  // protect Xs/Ws before next chunk overwrites
  }

  // ---- write pooled partials [b][tb][q][e]; D[q][e]: q = g*4+r, e col ----
#pragma unroll
  for (int nf = 0; nf < 4; ++nf) {
    const int e = w * 64 + nf * 16 + c16;
#pragma unroll
    for (int r = 0; r < 4; ++r) {
      const int q = g * 4 + r;
      partials[(((size_t)b * nt + tb) * Q_ + q) * E_ + e] = pacc[nf][r];
    }
  }
}

// ---------------- kernel 3: reduce partials + c-mapper + output -------------
__global__ __launch_bounds__(256) void tail_kernel(
    const float* __restrict__ partials, const float* __restrict__ Wc,
    const float* __restrict__ bc, const float* __restrict__ Wout,
    const float* __restrict__ bout, float* __restrict__ out, int nt) {
  int b = blockIdx.x, t = threadIdx.x;
  __shared__ float xp[Q_][E_ + 1];
  for (int q = 0; q < Q_; ++q) {
    float s = 0.f;
    for (int tb = 0; tb < nt; ++tb)
      s += partials[(((size_t)b * nt + tb) * Q_ + q) * E_ + t];
    xp[q][t] = s;
  }
  __syncthreads();
  for (int l = 0; l < LAY_; ++l) {
    const float* W = Wc + l * E_ * E_;
    float acc[Q_];
#pragma unroll
    for (int r = 0; r < Q_; ++r) acc[r] = 0.f;
    for (int k = 0; k < E_; ++k) {
      float wv = W[k * E_ + t];
#pragma unroll
      for (int r = 0; r < Q_; ++r) acc[r] += xp[r][k] * wv;
    }
    float be = bc[l * E_ + t];
    __syncthreads();
#pragma unroll
    for (int r = 0; r < Q_; ++r) xp[r][t] = fmaxf(acc[r] + be, 0.f) + xp[r][t];
    __syncthreads();
  }
  if (t < Q_ * NL_) {
    int q = t / NL_, n = t % NL_;
    float s = bout[n];
    for (int k = 0; k < E_; ++k) s += xp[q][k] * Wout[k * NL_ + n];
    out[(b * Q_ + q) * NL_ + n] = s;
  }
}

// ---------------- launch -----------------------------------------------------
extern "C" void kernel_launch(void* const* d_in, const int* in_sizes, int n_in,
                              void* d_out, int out_size, void* d_ws, size_t ws_size,
                              hipStream_t stream) {
  (void)in_sizes; (void)n_in; (void)out_size;
  const float* query    = (const float*)d_in[0];
  const float* features = (const float*)d_in[1];
  const float* values   = (const float*)d_in[2];
  const float* amask    = (const float*)d_in[3];
  const float* ftw      = (const float*)d_in[4];
  const float* Wq       = (const float*)d_in[5];
  const float* bq       = (const float*)d_in[6];
  const float* Wf       = (const float*)d_in[7];
  const float* bfb      = (const float*)d_in[8];
  const float* Wv       = (const float*)d_in[9];
  const float* bvb      = (const float*)d_in[10];
  const float* Wc       = (const float*)d_in[11];
  const float* bcb      = (const float*)d_in[12];
  const float* Wout     = (const float*)d_in[13];
  const float* bout     = (const float*)d_in[14];
  float* out = (float*)d_out;

  char* ws = (char*)d_ws;
  unsigned short* WtF = (unsigned short*)(ws);            // 256 KB
  unsigned short* WtV = (unsigned short*)(ws + 262144);   // 256 KB
  unsigned short* qmb = (unsigned short*)(ws + 524288);   // 256 KB
  float* partials     = (float*)(ws + 786432);

  // Pick NT (blocks per batch) by available workspace for fp32 partials.
  const size_t base = 786432;
  int nt;
  if (ws_size >= base + (size_t)B_ * 64 * Q_ * E_ * 4) nt = 64;        // 33.6 MB
  else if (ws_size >= base + (size_t)B_ * 32 * Q_ * E_ * 4) nt = 32;   // 16.8 MB
  else nt = 16;                                                         //  8.4 MB
  const int ch = 64 / nt;   // chunks per block; nt*ch*FT == F_

  prep_kernel<<<1024, 256, 0, stream>>>(Wf, Wv, WtF, WtV);
  qmap_kernel<<<B_, 256, 0, stream>>>(query, Wq, bq, qmb);
  fused_kernel<<<B_ * nt, TPB, 0, stream>>>(features, values, amask, ftw,
                                            WtF, bfb, WtV, bvb, qmb, partials, nt, ch);
  tail_kernel<<<B_, 256, 0, stream>>>(partials, Wc, bcb, Wout, bout, out, nt);
}

// Round 3
// 641.696 us; speedup vs baseline: 2.6538x; 2.6538x over previous
//
#include <hip/hip_runtime.h>
#include <hip/hip_bf16.h>

// B=32, Q=16, F=4096, E=256, NL=8, L=2 residual layers per mapper.
#define B_   32
#define Q_   16
#define F_   4096
#define E_   256
#define NL_  8
#define LAY_ 2
#define FT   64     // feature rows per chunk
#define NT   16     // tile-blocks per batch
#define CH   4      // chunks per block (NT*CH*FT == F_)
#define TPB  512    // 8 waves

typedef __attribute__((ext_vector_type(8))) __bf16 bf16x8_t;
typedef __attribute__((ext_vector_type(4))) __bf16 bf16x4_t;
typedef __attribute__((ext_vector_type(4))) float  f32x4;

// ---- LDS swizzle for a [64][256] bf16 tile (row stride 512 B) ----
__device__ __forceinline__ int swz(int r) {
  return ((r & 7) << 4) ^ (((r >> 3) & 3) << 5);
}
__device__ __forceinline__ int xoff(int r, int c2) {  // c2 = byte offset in row [0,512)
  return r * 512 + (c2 ^ swz(r));
}
__device__ __forceinline__ unsigned short f2bf_bits(float f) {
  __bf16 h = (__bf16)f;
  return __builtin_bit_cast(unsigned short, h);
}

// ---------------- kernel 0: weight prep (fp32 [l][k][n] -> bf16 [l][n][k]) ----
__global__ __launch_bounds__(256) void prep_kernel(
    const float* __restrict__ Wf, const float* __restrict__ Wv,
    unsigned short* __restrict__ WtF, unsigned short* __restrict__ WtV) {
  int idx = blockIdx.x * 256 + threadIdx.x;   // 4*65536 total
  int ml = idx >> 16;
  int r  = idx & 0xFFFF;
  int n  = r >> 8, k = r & 255;
  const float* src = (ml < 2) ? (Wf + ml * 65536) : (Wv + (ml - 2) * 65536);
  unsigned short* dst = (ml < 2) ? (WtF + ml * 65536) : (WtV + (ml - 2) * 65536);
  dst[n * 256 + k] = f2bf_bits(src[k * 256 + n]);
}

// ---------------- kernel 1: q mapper (fp32), store bf16 qm ------------------
__global__ __launch_bounds__(256) void qmap_kernel(
    const float* __restrict__ query, const float* __restrict__ Wq,
    const float* __restrict__ bq, unsigned short* __restrict__ qmb) {
  int b = blockIdx.x, t = threadIdx.x;
  __shared__ float xq[Q_][E_ + 1];
  for (int j = 0; j < Q_; ++j) xq[j][t] = query[(b * Q_ + j) * E_ + t];
  __syncthreads();
  for (int l = 0; l < LAY_; ++l) {
    const float* W = Wq + l * E_ * E_;
    float acc[Q_];
#pragma unroll
    for (int r = 0; r < Q_; ++r) acc[r] = 0.f;
    for (int k = 0; k < E_; ++k) {
      float wv = W[k * E_ + t];
#pragma unroll
      for (int r = 0; r < Q_; ++r) acc[r] += xq[r][k] * wv;
    }
    float be = bq[l * E_ + t];
    __syncthreads();
#pragma unroll
    for (int r = 0; r < Q_; ++r) xq[r][t] = fmaxf(acc[r] + be, 0.f) + xq[r][t];
    __syncthreads();
  }
  for (int j = 0; j < Q_; ++j) qmb[(b * Q_ + j) * E_ + t] = f2bf_bits(xq[j][t]);
}

// ---------------- staging: fp32 global tile -> bf16 swizzled LDS ------------
__device__ __forceinline__ void cvt_store(char* Xs, int r, int cb, const float* __restrict__ p) {
  const float4* s4 = (const float4*)p;
  float4 v0 = s4[0], v1 = s4[1];
  bf16x8_t t;
  t[0] = (__bf16)v0.x; t[1] = (__bf16)v0.y; t[2] = (__bf16)v0.z; t[3] = (__bf16)v0.w;
  t[4] = (__bf16)v1.x; t[5] = (__bf16)v1.y; t[6] = (__bf16)v1.z; t[7] = (__bf16)v1.w;
  *(bf16x8_t*)(Xs + xoff(r, cb)) = t;
}
__device__ __forceinline__ void stage_full(char* Xs, const float* __restrict__ src, int tid) {
#pragma unroll
  for (int j = 0; j < 4; ++j) {
    int u = j * 512 + tid;          // 2048 16B-units
    cvt_store(Xs, u >> 5, (u & 31) << 4, src + (u >> 5) * E_ + ((u & 31) << 3));
  }
}
__device__ __forceinline__ void stage_quarter(char* Xs, const float* __restrict__ src, int t4) {
#pragma unroll
  for (int j = 0; j < 8; ++j) {
    int u = j * 256 + t4;
    cvt_store(Xs, u >> 5, (u & 31) << 4, src + (u >> 5) * E_ + ((u & 31) << 3));
  }
}

// ---- Ping-pong residual layer: read Xin, write Xout (disjoint columns) -----
// Swapped orientation: A = W rows (e), B = X rows (m). D[e][m].
// Wave w owns e in [w*32, w*32+32). One barrier per layer (at end).
__device__ __forceinline__ void layer_pp(const char* __restrict__ Xin, char* __restrict__ Xout,
                                         const unsigned short* __restrict__ Wt,
                                         const float* __restrict__ bias, int w, int lane) {
  f32x4 acc[2][4];
#pragma unroll
  for (int ef = 0; ef < 2; ++ef)
#pragma unroll
    for (int mf = 0; mf < 4; ++mf) acc[ef][mf] = (f32x4){0.f, 0.f, 0.f, 0.f};
  const int c16 = lane & 15, g = lane >> 4, kb = g << 3;
#pragma unroll
  for (int ks = 0; ks < 8; ++ks) {
    const int k = ks * 32 + kb;
    bf16x8_t xb[4];
#pragma unroll
    for (int mf = 0; mf < 4; ++mf)
      xb[mf] = *(const bf16x8_t*)(Xin + xoff(mf * 16 + c16, k << 1));
#pragma unroll
    for (int ef = 0; ef < 2; ++ef) {
      const int e = w * 32 + ef * 16 + c16;
      bf16x8_t wa = *(const bf16x8_t*)(Wt + e * E_ + k);
#pragma unroll
      for (int mf = 0; mf < 4; ++mf)
        acc[ef][mf] = __builtin_amdgcn_mfma_f32_16x16x32_bf16(wa, xb[mf], acc[ef][mf], 0, 0, 0);
    }
  }
#pragma unroll
  for (int ef = 0; ef < 2; ++ef) {
    const int e0 = w * 32 + ef * 16 + (g << 2);
    const float4 b4 = *(const float4*)(bias + e0);
#pragma unroll
    for (int mf = 0; mf < 4; ++mf) {
      const int m = mf * 16 + c16;
      bf16x4_t old = *(const bf16x4_t*)(Xin + xoff(m, e0 << 1));
      bf16x4_t nw;
      nw[0] = (__bf16)(fmaxf(acc[ef][mf][0] + b4.x, 0.f) + (float)old[0]);
      nw[1] = (__bf16)(fmaxf(acc[ef][mf][1] + b4.y, 0.f) + (float)old[1]);
      nw[2] = (__bf16)(fmaxf(acc[ef][mf][2] + b4.z, 0.f) + (float)old[2]);
      nw[3] = (__bf16)(fmaxf(acc[ef][mf][3] + b4.w, 0.f) + (float)old[3]);
      *(bf16x4_t*)(Xout + xoff(m, e0 << 1)) = nw;
    }
  }
  __syncthreads();
}

// ---------------- fused main kernel -----------------------------------------
__global__ __launch_bounds__(TPB, 4) void fused_kernel(
    const float* __restrict__ features, const float* __restrict__ values,
    const float* __restrict__ amask, const float* __restrict__ ftw,
    const unsigned short* __restrict__ WtF, const float* __restrict__ bfb,
    const unsigned short* __restrict__ WtV, const float* __restrict__ bvb,
    const unsigned short* __restrict__ qmb, float* __restrict__ partials) {
  const int bid0 = blockIdx.x;
  const int bid = (bid0 & 7) * 64 + (bid0 >> 3);   // XCD-chunked swizzle (512 % 8 == 0)
  const int b = bid / NT, tb = bid % NT;
  const int tid = threadIdx.x;
  const int lane = tid & 63, w = tid >> 6;
  const int c16 = lane & 15, g = lane >> 4, kb = g << 3;

  __shared__ __align__(128) char X0[FT * 512];            // 32 KB
  __shared__ __align__(128) char X1[FT * 512];            // 32 KB
  __shared__ __align__(16) unsigned short Ws[Q_][FT + 8]; // attn weights [q][f] bf16

  f32x4 pacc[2];
  pacc[0] = (f32x4){0.f, 0.f, 0.f, 0.f};
  pacc[1] = (f32x4){0.f, 0.f, 0.f, 0.f};

  for (int c = 0; c < CH; ++c) {
    const int f0 = (tb * CH + c) * FT;

    // ---- features tile -> X0, f-mapper: X0 -> X1 -> X0 ----
    stage_full(X0, features + (size_t)(b * F_ + f0) * E_, tid);
    __syncthreads();
    layer_pp(X0, X1, WtF, bfb, w, lane);
    layer_pp(X1, X0, WtF + 65536, bfb + E_, w, lane);
    // Fm in X0.

    // ---- waves 0-3: S = qm @ Fm^T -> Ws   |  waves 4-7: stage values -> X1 ----
    if (w < 4) {
      f32x4 s = (f32x4){0.f, 0.f, 0.f, 0.f};
      const int fl = w * 16 + c16;
      const unsigned short* qbase = qmb + (size_t)(b * Q_ + c16) * E_ + kb;
#pragma unroll
      for (int ks = 0; ks < 8; ++ks) {
        bf16x8_t qa = *(const bf16x8_t*)(qbase + ks * 32);
        bf16x8_t xb = *(const bf16x8_t*)(X0 + xoff(fl, (ks * 32 + kb) << 1));
        s = __builtin_amdgcn_mfma_f32_16x16x32_bf16(qa, xb, s, 0, 0, 0);
      }
      const int fg = f0 + fl;
      const float lw = ftw[b * F_ + fg] * amask[b * F_ + fg];
#pragma unroll
      for (int r = 0; r < 4; ++r) {
        float sg = 1.f / (1.f + __expf(-s[r]));
        Ws[g * 4 + r][fl] = f2bf_bits(sg * lw);
      }
    } else {
      stage_quarter(X1, values + (size_t)(b * F_ + f0) * E_, tid - 256);
    }
    __syncthreads();

    // ---- v-mapper: X1 -> X0 -> X1 ----
    layer_pp(X1, X0, WtV, bvb, w, lane);
    layer_pp(X0, X1, WtV + 65536, bvb + E_, w, lane);
    // Vm in X1.

    // ---- P += Ws[16,FT] @ Vm[FT,256]; wave w owns e in [w*32, w*32+32) ----
#pragma unroll
    for (int ks = 0; ks < FT / 32; ++ks) {
      bf16x8_t a = *(const bf16x8_t*)&Ws[c16][ks * 32 + kb];
#pragma unroll
      for (int nf = 0; nf < 2; ++nf) {
        const int e = w * 32 + nf * 16 + c16;
        bf16x8_t bb;
#pragma unroll
        for (int i = 0; i < 8; ++i) {
          const int f = ks * 32 + kb + i;
          bb[i] = *(const __bf16*)(X1 + xoff(f, e << 1));
        }
        pacc[nf] = __builtin_amdgcn_mfma_f32_16x16x32_bf16(a, bb, pacc[nf], 0, 0, 0);
      }
    }
    // No barrier: next chunk stages into X0 (disjoint from X1/Ws), and its
    // stage-end barrier orders everything before X1/Ws are next written.
  }

  // ---- write pooled partials [b][tb][q][e]; D[q][e]: q = g*4+r ----
#pragma unroll
  for (int nf = 0; nf < 2; ++nf) {
    const int e = w * 32 + nf * 16 + c16;
#pragma unroll
    for (int r = 0; r < 4; ++r) {
      const int q = g * 4 + r;
      partials[(((size_t)b * NT + tb) * Q_ + q) * E_ + e] = pacc[nf][r];
    }
  }
}

// ---------------- kernel 3: parallel partial reduce -------------------------
__global__ __launch_bounds__(256) void reduce_kernel(
    const float* __restrict__ partials, float* __restrict__ pooled) {
  int idx = blockIdx.x * 256 + threadIdx.x;   // B_*Q_*E_ = 131072
  int e = idx & 255, q = (idx >> 8) & 15, b = idx >> 12;
  float s = 0.f;
#pragma unroll 4
  for (int tb = 0; tb < NT; ++tb)
    s += partials[(((size_t)(b * NT + tb)) * Q_ + q) * E_ + e];
  pooled[idx] = s;
}

// ---------------- kernel 4: c-mapper + output projection --------------------
__global__ __launch_bounds__(256) void tail_kernel(
    const float* __restrict__ pooled, const float* __restrict__ Wc,
    const float* __restrict__ bc, const float* __restrict__ Wout,
    const float* __restrict__ bout, float* __restrict__ out) {
  int b = blockIdx.x, t = threadIdx.x;
  __shared__ float xp[Q_][E_ + 1];
  for (int q = 0; q < Q_; ++q) xp[q][t] = pooled[(b * Q_ + q) * E_ + t];
  __syncthreads();
  for (int l = 0; l < LAY_; ++l) {
    const float* W = Wc + l * E_ * E_;
    float acc[Q_];
#pragma unroll
    for (int r = 0; r < Q_; ++r) acc[r] = 0.f;
    for (int k = 0; k < E_; ++k) {
      float wv = W[k * E_ + t];
#pragma unroll
      for (int r = 0; r < Q_; ++r) acc[r] += xp[r][k] * wv;
    }
    float be = bc[l * E_ + t];
    __syncthreads();
#pragma unroll
    for (int r = 0; r < Q_; ++r) xp[r][t] = fmaxf(acc[r] + be, 0.f) + xp[r][t];
    __syncthreads();
  }
  if (t < Q_ * NL_) {
    int q = t / NL_, n = t % NL_;
    float s = bout[n];
    for (int k = 0; k < E_; ++k) s += xp[q][k] * Wout[k * NL_ + n];
    out[(b * Q_ + q) * NL_ + n] = s;
  }
}

// ---------------- launch -----------------------------------------------------
extern "C" void kernel_launch(void* const* d_in, const int* in_sizes, int n_in,
                              void* d_out, int out_size, void* d_ws, size_t ws_size,
                              hipStream_t stream) {
  (void)in_sizes; (void)n_in; (void)out_size; (void)ws_size;
  const float* query    = (const float*)d_in[0];
  const float* features = (const float*)d_in[1];
  const float* values   = (const float*)d_in[2];
  const float* amask    = (const float*)d_in[3];
  const float* ftw      = (const float*)d_in[4];
  const float* Wq       = (const float*)d_in[5];
  const float* bq       = (const float*)d_in[6];
  const float* Wf       = (const float*)d_in[7];
  const float* bfb      = (const float*)d_in[8];
  const float* Wv       = (const float*)d_in[9];
  const float* bvb      = (const float*)d_in[10];
  const float* Wc       = (const float*)d_in[11];
  const float* bcb      = (const float*)d_in[12];
  const float* Wout     = (const float*)d_in[13];
  const float* bout     = (const float*)d_in[14];
  float* out = (float*)d_out;

  char* ws = (char*)d_ws;
  unsigned short* WtF = (unsigned short*)(ws);             // 256 KB
  unsigned short* WtV = (unsigned short*)(ws + 262144);    // 256 KB
  unsigned short* qmb = (unsigned short*)(ws + 524288);    // 256 KB
  float* pooled       = (float*)(ws + 786432);             // 512 KB
  float* partials     = (float*)(ws + 1310720);            // 8.4 MB

  prep_kernel<<<1024, 256, 0, stream>>>(Wf, Wv, WtF, WtV);
  qmap_kernel<<<B_, 256, 0, stream>>>(query, Wq, bq, qmb);
  fused_kernel<<<B_ * NT, TPB, 0, stream>>>(features, values, amask, ftw,
                                            WtF, bfb, WtV, bvb, qmb, partials);
  reduce_kernel<<<(B_ * Q_ * E_) / 256, 256, 0, stream>>>(partials, pooled);
  tail_kernel<<<B_, 256, 0, stream>>>(pooled, Wc, bcb, Wout, bout, out);
}

// Round 4
// 632.843 us; speedup vs baseline: 2.6910x; 1.0140x over previous
//
#include <hip/hip_runtime.h>
#include <hip/hip_bf16.h>

// B=32, Q=16, F=4096, E=256, NL=8, L=2 residual layers per mapper.
#define B_   32
#define Q_   16
#define F_   4096
#define E_   256
#define NL_  8
#define LAY_ 2
#define FT   64     // feature rows per chunk
#define NT   16     // tile-blocks per batch
#define CH   4      // chunks per block (NT*CH*FT == F_)
#define TPB  512    // 8 waves
#define TILE_BYTES 32768   // FT * 512

typedef __attribute__((ext_vector_type(8))) __bf16 bf16x8_t;
typedef __attribute__((ext_vector_type(4))) __bf16 bf16x4_t;
typedef __attribute__((ext_vector_type(4))) float  f32x4;

// ---- LDS swizzle for a [64][256] bf16 tile (row stride 512 B) ----
__device__ __forceinline__ int swz(int r) {
  return ((r & 7) << 4) ^ (((r >> 3) & 3) << 5);
}
__device__ __forceinline__ int xoff(int r, int c2) {  // c2 = byte offset in row [0,512)
  return r * 512 + (c2 ^ swz(r));
}
__device__ __forceinline__ unsigned short f2bf_bits(float f) {
  __bf16 h = (__bf16)f;
  return __builtin_bit_cast(unsigned short, h);
}

// ---------------- combined prep kernel --------------------------------------
// blocks [0, inB): fp32 inputs -> bf16 pre-swizzled tile images (if enabled)
// blocks [inB, inB+1024): weight transpose fp32 [l][k][n] -> bf16 [l][n][k]
// blocks [inB+1024, inB+1056): q-mapper (fp32) -> bf16 qm
__global__ __launch_bounds__(256) void prep_all_kernel(
    const float* __restrict__ features, const float* __restrict__ values,
    unsigned short* __restrict__ fimg, unsigned short* __restrict__ vimg,
    const float* __restrict__ Wf, const float* __restrict__ Wv,
    unsigned short* __restrict__ WtF, unsigned short* __restrict__ WtV,
    const float* __restrict__ query, const float* __restrict__ Wq,
    const float* __restrict__ bq, unsigned short* __restrict__ qmb,
    int inB) {
  const int blk = blockIdx.x;
  const int t = threadIdx.x;
  if (blk < inB) {
    // ---- input tile images: 8192 blocks x 256 thr x 4 units of 16B out ----
#pragma unroll
    for (int j = 0; j < 4; ++j) {
      int u = blk * 1024 + j * 256 + t;           // global 16B-unit id
      int tensor = u >> 22;                       // 4M units per tensor
      int wu = u & 4194303;
      int tile = wu >> 11;                        // 2048 units per tile
      int v = wu & 2047;
      int rr = v >> 5;                            // row in tile
      int cb = (v & 31) << 4;                     // byte in row
      const float* src = (tensor == 0 ? features : values)
                         + ((size_t)(tile * 64 + rr)) * E_ + ((v & 31) << 3);
      const float4* s4 = (const float4*)src;
      float4 v0 = s4[0], v1 = s4[1];
      bf16x8_t o;
      o[0] = (__bf16)v0.x; o[1] = (__bf16)v0.y; o[2] = (__bf16)v0.z; o[3] = (__bf16)v0.w;
      o[4] = (__bf16)v1.x; o[5] = (__bf16)v1.y; o[6] = (__bf16)v1.z; o[7] = (__bf16)v1.w;
      char* dst = (char*)(tensor == 0 ? fimg : vimg);
      *(bf16x8_t*)(dst + (size_t)tile * TILE_BYTES + xoff(rr, cb)) = o;
    }
  } else if (blk < inB + 1024) {
    int idx = (blk - inB) * 256 + t;              // 4*65536 total
    int ml = idx >> 16;
    int r  = idx & 0xFFFF;
    int n  = r >> 8, k = r & 255;
    const float* src = (ml < 2) ? (Wf + ml * 65536) : (Wv + (ml - 2) * 65536);
    unsigned short* dst = (ml < 2) ? (WtF + ml * 65536) : (WtV + (ml - 2) * 65536);
    dst[n * 256 + k] = f2bf_bits(src[k * 256 + n]);
  } else {
    // ---- q mapper ----
    int b = blk - inB - 1024;
    __shared__ float xq[Q_][E_ + 1];
    for (int j = 0; j < Q_; ++j) xq[j][t] = query[(b * Q_ + j) * E_ + t];
    __syncthreads();
    for (int l = 0; l < LAY_; ++l) {
      const float* W = Wq + l * E_ * E_;
      float acc[Q_];
#pragma unroll
      for (int r = 0; r < Q_; ++r) acc[r] = 0.f;
      for (int k = 0; k < E_; ++k) {
        float wv = W[k * E_ + t];
#pragma unroll
        for (int r = 0; r < Q_; ++r) acc[r] += xq[r][k] * wv;
      }
      float be = bq[l * E_ + t];
      __syncthreads();
#pragma unroll
      for (int r = 0; r < Q_; ++r) xq[r][t] = fmaxf(acc[r] + be, 0.f) + xq[r][t];
      __syncthreads();
    }
    for (int j = 0; j < Q_; ++j) qmb[(b * Q_ + j) * E_ + t] = f2bf_bits(xq[j][t]);
  }
}

// ---------------- async staging: bf16 tile image -> LDS (linear) ------------
__device__ __forceinline__ void stage_async(char* Xs, const char* img, int w, int lane) {
#pragma unroll
  for (int j = 0; j < 4; ++j) {
    const char* g = img + (w * 4096 + j * 1024) + lane * 16;
    char* l = Xs + w * 4096 + j * 1024;   // wave-uniform base; HW adds lane*16
    __builtin_amdgcn_global_load_lds(
        (const __attribute__((address_space(1))) void*)g,
        (__attribute__((address_space(3))) void*)l, 16, 0, 0);
  }
}

// ---- Ping-pong residual layer: read Xin, write Xout (disjoint buffers) -----
// Swapped orientation: A = W rows (e), B = X rows (m). D[e][m].
// Wave w owns e in [w*32, w*32+32). One barrier per layer (at end).
__device__ __forceinline__ void layer_pp(const char* __restrict__ Xin, char* __restrict__ Xout,
                                         const unsigned short* __restrict__ Wt,
                                         const float* __restrict__ bias, int w, int lane) {
  f32x4 acc[2][4];
#pragma unroll
  for (int ef = 0; ef < 2; ++ef)
#pragma unroll
    for (int mf = 0; mf < 4; ++mf) acc[ef][mf] = (f32x4){0.f, 0.f, 0.f, 0.f};
  const int c16 = lane & 15, g = lane >> 4, kb = g << 3;
#pragma unroll
  for (int ks = 0; ks < 8; ++ks) {
    const int k = ks * 32 + kb;
    bf16x8_t xb[4];
#pragma unroll
    for (int mf = 0; mf < 4; ++mf)
      xb[mf] = *(const bf16x8_t*)(Xin + xoff(mf * 16 + c16, k << 1));
#pragma unroll
    for (int ef = 0; ef < 2; ++ef) {
      const int e = w * 32 + ef * 16 + c16;
      bf16x8_t wa = *(const bf16x8_t*)(Wt + e * E_ + k);
#pragma unroll
      for (int mf = 0; mf < 4; ++mf)
        acc[ef][mf] = __builtin_amdgcn_mfma_f32_16x16x32_bf16(wa, xb[mf], acc[ef][mf], 0, 0, 0);
    }
  }
#pragma unroll
  for (int ef = 0; ef < 2; ++ef) {
    const int e0 = w * 32 + ef * 16 + (g << 2);
    const float4 b4 = *(const float4*)(bias + e0);
#pragma unroll
    for (int mf = 0; mf < 4; ++mf) {
      const int m = mf * 16 + c16;
      bf16x4_t old = *(const bf16x4_t*)(Xin + xoff(m, e0 << 1));
      bf16x4_t nw;
      nw[0] = (__bf16)(fmaxf(acc[ef][mf][0] + b4.x, 0.f) + (float)old[0]);
      nw[1] = (__bf16)(fmaxf(acc[ef][mf][1] + b4.y, 0.f) + (float)old[1]);
      nw[2] = (__bf16)(fmaxf(acc[ef][mf][2] + b4.z, 0.f) + (float)old[2]);
      nw[3] = (__bf16)(fmaxf(acc[ef][mf][3] + b4.w, 0.f) + (float)old[3]);
      *(bf16x4_t*)(Xout + xoff(m, e0 << 1)) = nw;
    }
  }
  __syncthreads();
}

// ---------------- fused main kernel (async, bf16 images) --------------------
__global__ __launch_bounds__(TPB, 4) void fused_async(
    const unsigned short* __restrict__ fimg, const unsigned short* __restrict__ vimg,
    const float* __restrict__ amask, const float* __restrict__ ftw,
    const unsigned short* __restrict__ WtF, const float* __restrict__ bfb,
    const unsigned short* __restrict__ WtV, const float* __restrict__ bvb,
    const unsigned short* __restrict__ qmb, float* __restrict__ partials) {
  const int bid0 = blockIdx.x;
  const int bid = (bid0 & 7) * 64 + (bid0 >> 3);   // XCD-chunked swizzle (512 % 8 == 0)
  const int b = bid / NT, tb = bid % NT;
  const int tid = threadIdx.x;
  const int lane = tid & 63, w = tid >> 6;
  const int c16 = lane & 15, g = lane >> 4, kb = g << 3;

  __shared__ __align__(128) char X0[TILE_BYTES];          // 32 KB
  __shared__ __align__(128) char X1[TILE_BYTES];          // 32 KB
  __shared__ __align__(16) unsigned short Ws[Q_][FT + 8]; // attn weights [q][f] bf16

  const char* fimgB = (const char*)fimg + (size_t)(b * 64 + tb * CH) * TILE_BYTES;
  const char* vimgB = (const char*)vimg + (size_t)(b * 64 + tb * CH) * TILE_BYTES;

  f32x4 pacc[2];
  pacc[0] = (f32x4){0.f, 0.f, 0.f, 0.f};
  pacc[1] = (f32x4){0.f, 0.f, 0.f, 0.f};

  // prologue: stage features tile 0
  stage_async(X0, fimgB, w, lane);
  __syncthreads();   // drains vmcnt

  for (int c = 0; c < CH; ++c) {
    const int f0 = (tb * CH + c) * FT;

    // ---- f-mapper: X0 -> X1 -> X0 (Fm in X0) ----
    layer_pp(X0, X1, WtF, bfb, w, lane);
    layer_pp(X1, X0, WtF + 65536, bfb + E_, w, lane);

    // ---- issue V-tile loads into X1 (dead after L2's barrier) ----
    stage_async(X1, vimgB + c * TILE_BYTES, w, lane);

    // ---- waves 0-3: S = qm @ Fm^T -> Ws (reads X0 only) ----
    if (w < 4) {
      f32x4 s = (f32x4){0.f, 0.f, 0.f, 0.f};
      const int fl = w * 16 + c16;
      const unsigned short* qbase = qmb + (size_t)(b * Q_ + c16) * E_ + kb;
#pragma unroll
      for (int ks = 0; ks < 8; ++ks) {
        bf16x8_t qa = *(const bf16x8_t*)(qbase + ks * 32);
        bf16x8_t xb = *(const bf16x8_t*)(X0 + xoff(fl, (ks * 32 + kb) << 1));
        s = __builtin_amdgcn_mfma_f32_16x16x32_bf16(qa, xb, s, 0, 0, 0);
      }
      const int fg = f0 + fl;
      const float lw = ftw[b * F_ + fg] * amask[b * F_ + fg];
#pragma unroll
      for (int r = 0; r < 4; ++r) {
        float sg = 1.f / (1.f + __expf(-s[r]));
        Ws[g * 4 + r][fl] = f2bf_bits(sg * lw);
      }
    }
    __syncthreads();   // drains V-tile vmcnt; X1 = values tile, Ws ready

    // ---- v-mapper: X1 -> X0 -> X1 (Vm in X1) ----
    layer_pp(X1, X0, WtV, bvb, w, lane);
    layer_pp(X0, X1, WtV + 65536, bvb + E_, w, lane);

    // ---- issue next chunk's features loads into X0 (dead after VL2) ----
    if (c + 1 < CH) stage_async(X0, fimgB + (c + 1) * TILE_BYTES, w, lane);

    // ---- P += Ws[16,FT] @ Vm[FT,256]; wave w owns e in [w*32, w*32+32) ----
#pragma unroll
    for (int ks = 0; ks < FT / 32; ++ks) {
      bf16x8_t a = *(const bf16x8_t*)&Ws[c16][ks * 32 + kb];
#pragma unroll
      for (int nf = 0; nf < 2; ++nf) {
        const int e = w * 32 + nf * 16 + c16;
        bf16x8_t bb;
#pragma unroll
        for (int i = 0; i < 8; ++i) {
          const int f = ks * 32 + kb + i;
          bb[i] = *(const __bf16*)(X1 + xoff(f, e << 1));
        }
        pacc[nf] = __builtin_amdgcn_mfma_f32_16x16x32_bf16(a, bb, pacc[nf], 0, 0, 0);
      }
    }
    __syncthreads();   // drains next-feat vmcnt; X0 ready for next chunk
  }

  // ---- write pooled partials [b][tb][q][e]; D[q][e]: q = g*4+r ----
#pragma unroll
  for (int nf = 0; nf < 2; ++nf) {
    const int e = w * 32 + nf * 16 + c16;
#pragma unroll
    for (int r = 0; r < 4; ++r) {
      const int q = g * 4 + r;
      partials[(((size_t)b * NT + tb) * Q_ + q) * E_ + e] = pacc[nf][r];
    }
  }
}

// ---------------- fallback: synchronous fused kernel (R3-proven) ------------
__device__ __forceinline__ void cvt_store(char* Xs, int r, int cb, const float* __restrict__ p) {
  const float4* s4 = (const float4*)p;
  float4 v0 = s4[0], v1 = s4[1];
  bf16x8_t o;
  o[0] = (__bf16)v0.x; o[1] = (__bf16)v0.y; o[2] = (__bf16)v0.z; o[3] = (__bf16)v0.w;
  o[4] = (__bf16)v1.x; o[5] = (__bf16)v1.y; o[6] = (__bf16)v1.z; o[7] = (__bf16)v1.w;
  *(bf16x8_t*)(Xs + xoff(r, cb)) = o;
}
__global__ __launch_bounds__(TPB, 4) void fused_sync(
    const float* __restrict__ features, const float* __restrict__ values,
    const float* __restrict__ amask, const float* __restrict__ ftw,
    const unsigned short* __restrict__ WtF, const float* __restrict__ bfb,
    const unsigned short* __restrict__ WtV, const float* __restrict__ bvb,
    const unsigned short* __restrict__ qmb, float* __restrict__ partials) {
  const int bid0 = blockIdx.x;
  const int bid = (bid0 & 7) * 64 + (bid0 >> 3);
  const int b = bid / NT, tb = bid % NT;
  const int tid = threadIdx.x;
  const int lane = tid & 63, w = tid >> 6;
  const int c16 = lane & 15, g = lane >> 4, kb = g << 3;

  __shared__ __align__(128) char X0[TILE_BYTES];
  __shared__ __align__(128) char X1[TILE_BYTES];
  __shared__ __align__(16) unsigned short Ws[Q_][FT + 8];

  f32x4 pacc[2];
  pacc[0] = (f32x4){0.f, 0.f, 0.f, 0.f};
  pacc[1] = (f32x4){0.f, 0.f, 0.f, 0.f};

  for (int c = 0; c < CH; ++c) {
    const int f0 = (tb * CH + c) * FT;
#pragma unroll
    for (int j = 0; j < 4; ++j) {
      int u = j * 512 + tid;
      cvt_store(X0, u >> 5, (u & 31) << 4,
                features + (size_t)(b * F_ + f0) * E_ + (u >> 5) * E_ + ((u & 31) << 3));
    }
    __syncthreads();
    layer_pp(X0, X1, WtF, bfb, w, lane);
    layer_pp(X1, X0, WtF + 65536, bfb + E_, w, lane);
    if (w < 4) {
      f32x4 s = (f32x4){0.f, 0.f, 0.f, 0.f};
      const int fl = w * 16 + c16;
      const unsigned short* qbase = qmb + (size_t)(b * Q_ + c16) * E_ + kb;
#pragma unroll
      for (int ks = 0; ks < 8; ++ks) {
        bf16x8_t qa = *(const bf16x8_t*)(qbase + ks * 32);
        bf16x8_t xb = *(const bf16x8_t*)(X0 + xoff(fl, (ks * 32 + kb) << 1));
        s = __builtin_amdgcn_mfma_f32_16x16x32_bf16(qa, xb, s, 0, 0, 0);
      }
      const int fg = f0 + fl;
      const float lw = ftw[b * F_ + fg] * amask[b * F_ + fg];
#pragma unroll
      for (int r = 0; r < 4; ++r) {
        float sg = 1.f / (1.f + __expf(-s[r]));
        Ws[g * 4 + r][fl] = f2bf_bits(sg * lw);
      }
    } else {
      const int t4 = tid - 256;
#pragma unroll
      for (int j = 0; j < 8; ++j) {
        int u = j * 256 + t4;
        cvt_store(X1, u >> 5, (u & 31) << 4,
                  values + (size_t)(b * F_ + f0) * E_ + (u >> 5) * E_ + ((u & 31) << 3));
      }
    }
    __syncthreads();
    layer_pp(X1, X0, WtV, bvb, w, lane);
    layer_pp(X0, X1, WtV + 65536, bvb + E_, w, lane);
#pragma unroll
    for (int ks = 0; ks < FT / 32; ++ks) {
      bf16x8_t a = *(const bf16x8_t*)&Ws[c16][ks * 32 + kb];
#pragma unroll
      for (int nf = 0; nf < 2; ++nf) {
        const int e = w * 32 + nf * 16 + c16;
        bf16x8_t bb;
#pragma unroll
        for (int i = 0; i < 8; ++i) {
          const int f = ks * 32 + kb + i;
          bb[i] = *(const __bf16*)(X1 + xoff(f, e << 1));
        }
        pacc[nf] = __builtin_amdgcn_mfma_f32_16x16x32_bf16(a, bb, pacc[nf], 0, 0, 0);
      }
    }
    __syncthreads();
  }
#pragma unroll
  for (int nf = 0; nf < 2; ++nf) {
    const int e = w * 32 + nf * 16 + c16;
#pragma unroll
    for (int r = 0; r < 4; ++r) {
      const int q = g * 4 + r;
      partials[(((size_t)b * NT + tb) * Q_ + q) * E_ + e] = pacc[nf][r];
    }
  }
}

// ---------------- parallel partial reduce -----------------------------------
__global__ __launch_bounds__(256) void reduce_kernel(
    const float* __restrict__ partials, float* __restrict__ pooled) {
  int idx = blockIdx.x * 256 + threadIdx.x;   // B_*Q_*E_ = 131072
  int e = idx & 255, q = (idx >> 8) & 15, b = idx >> 12;
  float s = 0.f;
#pragma unroll 4
  for (int tb = 0; tb < NT; ++tb)
    s += partials[(((size_t)(b * NT + tb)) * Q_ + q) * E_ + e];
  pooled[idx] = s;
}

// ---------------- c-mapper + output projection ------------------------------
__global__ __launch_bounds__(256) void tail_kernel(
    const float* __restrict__ pooled, const float* __restrict__ Wc,
    const float* __restrict__ bc, const float* __restrict__ Wout,
    const float* __restrict__ bout, float* __restrict__ out) {
  int b = blockIdx.x, t = threadIdx.x;
  __shared__ float xp[Q_][E_ + 1];
  for (int q = 0; q < Q_; ++q) xp[q][t] = pooled[(b * Q_ + q) * E_ + t];
  __syncthreads();
  for (int l = 0; l < LAY_; ++l) {
    const float* W = Wc + l * E_ * E_;
    float acc[Q_];
#pragma unroll
    for (int r = 0; r < Q_; ++r) acc[r] = 0.f;
    for (int k = 0; k < E_; ++k) {
      float wv = W[k * E_ + t];
#pragma unroll
      for (int r = 0; r < Q_; ++r) acc[r] += xp[r][k] * wv;
    }
    float be = bc[l * E_ + t];
    __syncthreads();
#pragma unroll
    for (int r = 0; r < Q_; ++r) xp[r][t] = fmaxf(acc[r] + be, 0.f) + xp[r][t];
    __syncthreads();
  }
  if (t < Q_ * NL_) {
    int q = t / NL_, n = t % NL_;
    float s = bout[n];
    for (int k = 0; k < E_; ++k) s += xp[q][k] * Wout[k * NL_ + n];
    out[(b * Q_ + q) * NL_ + n] = s;
  }
}

// ---------------- launch -----------------------------------------------------
extern "C" void kernel_launch(void* const* d_in, const int* in_sizes, int n_in,
                              void* d_out, int out_size, void* d_ws, size_t ws_size,
                              hipStream_t stream) {
  (void)in_sizes; (void)n_in; (void)out_size;
  const float* query    = (const float*)d_in[0];
  const float* features = (const float*)d_in[1];
  const float* values   = (const float*)d_in[2];
  const float* amask    = (const float*)d_in[3];
  const float* ftw      = (const float*)d_in[4];
  const float* Wq       = (const float*)d_in[5];
  const float* bq       = (const float*)d_in[6];
  const float* Wf       = (const float*)d_in[7];
  const float* bfb      = (const float*)d_in[8];
  const float* Wv       = (const float*)d_in[9];
  const float* bvb      = (const float*)d_in[10];
  const float* Wc       = (const float*)d_in[11];
  const float* bcb      = (const float*)d_in[12];
  const float* Wout     = (const float*)d_in[13];
  const float* bout     = (const float*)d_in[14];
  float* out = (float*)d_out;

  char* ws = (char*)d_ws;
  unsigned short* WtF = (unsigned short*)(ws);             // 256 KB
  unsigned short* WtV = (unsigned short*)(ws + 262144);    // 256 KB
  unsigned short* qmb = (unsigned short*)(ws + 524288);    // 256 KB
  float* pooled       = (float*)(ws + 786432);             // 512 KB
  float* partials     = (float*)(ws + 1310720);            // 8.4 MB -> ends 9699328
  unsigned short* fimg = (unsigned short*)(ws + 9699328);  // 64 MB
  unsigned short* vimg = (unsigned short*)(ws + 9699328 + 67108864);  // 64 MB
  const size_t need_async = 9699328 + 2ull * 67108864;

  const bool async_ok = (ws_size >= need_async);
  const int inB = async_ok ? 8192 : 0;

  prep_all_kernel<<<inB + 1024 + B_, 256, 0, stream>>>(
      features, values, fimg, vimg, Wf, Wv, WtF, WtV, query, Wq, bq, qmb, inB);

  if (async_ok) {
    fused_async<<<B_ * NT, TPB, 0, stream>>>(fimg, vimg, amask, ftw,
                                             WtF, bfb, WtV, bvb, qmb, partials);
  } else {
    fused_sync<<<B_ * NT, TPB, 0, stream>>>(features, values, amask, ftw,
                                            WtF, bfb, WtV, bvb, qmb, partials);
  }
  reduce_kernel<<<(B_ * Q_ * E_) / 256, 256, 0, stream>>>(partials, pooled);
  tail_kernel<<<B_, 256, 0, stream>>>(pooled, Wc, bcb, Wout, bout, out);
}

// Round 5
// 619.587 us; speedup vs baseline: 2.7485x; 1.0214x over previous
//
#include <hip/hip_runtime.h>
#include <hip/hip_bf16.h>

// B=32, Q=16, F=4096, E=256, NL=8, L=2 residual layers per mapper.
#define B_   32
#define Q_   16
#define F_   4096
#define E_   256
#define NL_  8
#define LAY_ 2
#define FT   64     // feature rows per chunk
#define NT   16     // tile-blocks per batch
#define CH   4      // chunks per block (NT*CH*FT == F_)
#define TPB  512    // 8 waves
#define TILE_BYTES 32768   // FT * 512

typedef __attribute__((ext_vector_type(8))) __bf16 bf16x8_t;
typedef __attribute__((ext_vector_type(4))) __bf16 bf16x4_t;
typedef __attribute__((ext_vector_type(4))) float  f32x4;

// ---- LDS swizzle for a [64][256] bf16 tile (row stride 512 B) ----
__device__ __forceinline__ int swz(int r) {
  return ((r & 7) << 4) ^ (((r >> 3) & 3) << 5);
}
__device__ __forceinline__ int xoff(int r, int c2) {  // c2 = byte offset in row [0,512)
  return r * 512 + (c2 ^ swz(r));
}
__device__ __forceinline__ unsigned short f2bf_bits(float f) {
  __bf16 h = (__bf16)f;
  return __builtin_bit_cast(unsigned short, h);
}

// ---------------- combined prep kernel --------------------------------------
// [0,inB): fp32 inputs -> bf16 pre-swizzled tile images (NT loads)
// [inB, inB+1024): Wf/Wv transpose fp32 [l][k][n] -> bf16 [l][n][k]
// [inB+1024, inB+1536): Wc transpose fp32 -> fp32 WcT [l][n][k]
// [inB+1536, +B_): q-mapper (fp32) -> bf16 qm
__global__ __launch_bounds__(256) void prep_all_kernel(
    const float* __restrict__ features, const float* __restrict__ values,
    unsigned short* __restrict__ fimg, unsigned short* __restrict__ vimg,
    const float* __restrict__ Wf, const float* __restrict__ Wv,
    unsigned short* __restrict__ WtF, unsigned short* __restrict__ WtV,
    const float* __restrict__ Wc, float* __restrict__ WcT,
    const float* __restrict__ query, const float* __restrict__ Wq,
    const float* __restrict__ bq, unsigned short* __restrict__ qmb,
    int inB) {
  const int blk = blockIdx.x;
  const int t = threadIdx.x;
  if (blk < inB) {
#pragma unroll
    for (int j = 0; j < 4; ++j) {
      int u = blk * 1024 + j * 256 + t;           // global 16B-unit id
      int tensor = u >> 22;                       // 4M units per tensor
      int wu = u & 4194303;
      int tile = wu >> 11;                        // 2048 units per tile
      int v = wu & 2047;
      int rr = v >> 5;                            // row in tile
      int cb = (v & 31) << 4;                     // byte in row
      const f32x4* src = (const f32x4*)((tensor == 0 ? features : values)
                         + ((size_t)(tile * 64 + rr)) * E_ + ((v & 31) << 3));
      f32x4 v0 = __builtin_nontemporal_load(src);
      f32x4 v1 = __builtin_nontemporal_load(src + 1);
      bf16x8_t o;
      o[0] = (__bf16)v0[0]; o[1] = (__bf16)v0[1]; o[2] = (__bf16)v0[2]; o[3] = (__bf16)v0[3];
      o[4] = (__bf16)v1[0]; o[5] = (__bf16)v1[1]; o[6] = (__bf16)v1[2]; o[7] = (__bf16)v1[3];
      char* dst = (char*)(tensor == 0 ? fimg : vimg);
      *(bf16x8_t*)(dst + (size_t)tile * TILE_BYTES + xoff(rr, cb)) = o;
    }
  } else if (blk < inB + 1024) {
    int idx = (blk - inB) * 256 + t;              // 4*65536 total
    int ml = idx >> 16;
    int r  = idx & 0xFFFF;
    int n  = r >> 8, k = r & 255;
    const float* src = (ml < 2) ? (Wf + ml * 65536) : (Wv + (ml - 2) * 65536);
    unsigned short* dst = (ml < 2) ? (WtF + ml * 65536) : (WtV + (ml - 2) * 65536);
    dst[n * 256 + k] = f2bf_bits(src[k * 256 + n]);
  } else if (blk < inB + 1536) {
    int idx = (blk - inB - 1024) * 256 + t;       // 2*65536 total
    int l = idx >> 16;
    int r = idx & 0xFFFF;
    int n = r >> 8, k = r & 255;
    WcT[l * 65536 + n * 256 + k] = Wc[l * 65536 + k * 256 + n];
  } else {
    // ---- q mapper ----
    int b = blk - inB - 1536;
    __shared__ float xq[Q_][E_ + 1];
    for (int j = 0; j < Q_; ++j) xq[j][t] = query[(b * Q_ + j) * E_ + t];
    __syncthreads();
    for (int l = 0; l < LAY_; ++l) {
      const float* W = Wq + l * E_ * E_;
      float acc[Q_];
#pragma unroll
      for (int r = 0; r < Q_; ++r) acc[r] = 0.f;
      for (int k = 0; k < E_; ++k) {
        float wv = W[k * E_ + t];
#pragma unroll
        for (int r = 0; r < Q_; ++r) acc[r] += xq[r][k] * wv;
      }
      float be = bq[l * E_ + t];
      __syncthreads();
#pragma unroll
      for (int r = 0; r < Q_; ++r) xq[r][t] = fmaxf(acc[r] + be, 0.f) + xq[r][t];
      __syncthreads();
    }
    for (int j = 0; j < Q_; ++j) qmb[(b * Q_ + j) * E_ + t] = f2bf_bits(xq[j][t]);
  }
}

// ---------------- async staging: bf16 tile image -> LDS (linear, NT) --------
__device__ __forceinline__ void stage_async(char* Xs, const char* img, int w, int lane) {
#pragma unroll
  for (int j = 0; j < 4; ++j) {
    const char* g = img + (w * 4096 + j * 1024) + lane * 16;
    char* l = Xs + w * 4096 + j * 1024;   // wave-uniform base; HW adds lane*16
    __builtin_amdgcn_global_load_lds(
        (const __attribute__((address_space(1))) void*)g,
        (__attribute__((address_space(3))) void*)l, 16, 0, 2 /*NT*/);
  }
}

// ---- Ping-pong residual layer: read Xin, write Xout (disjoint buffers) -----
// Swapped orientation: A = W rows (e), B = X rows (m). D[e][m].
// Wave w owns e in [w*32, w*32+32). All 16 weight fragments preloaded up
// front (no barrier dependency) so their latency overlaps the LDS reads.
__device__ __forceinline__ void layer_pp(const char* __restrict__ Xin, char* __restrict__ Xout,
                                         const unsigned short* __restrict__ Wt,
                                         const float* __restrict__ bias, int w, int lane) {
  const int c16 = lane & 15, g = lane >> 4, kb = g << 3;
  const unsigned short* wrow0 = Wt + (w * 32 + c16) * E_ + kb;
  const unsigned short* wrow1 = Wt + (w * 32 + 16 + c16) * E_ + kb;

  bf16x8_t wa[8][2];
#pragma unroll
  for (int ks = 0; ks < 8; ++ks) {
    wa[ks][0] = *(const bf16x8_t*)(wrow0 + ks * 32);
    wa[ks][1] = *(const bf16x8_t*)(wrow1 + ks * 32);
  }

  f32x4 acc[2][4];
#pragma unroll
  for (int ef = 0; ef < 2; ++ef)
#pragma unroll
    for (int mf = 0; mf < 4; ++mf) acc[ef][mf] = (f32x4){0.f, 0.f, 0.f, 0.f};

#pragma unroll
  for (int ks = 0; ks < 8; ++ks) {
    const int k = ks * 32 + kb;
    bf16x8_t xb[4];
#pragma unroll
    for (int mf = 0; mf < 4; ++mf)
      xb[mf] = *(const bf16x8_t*)(Xin + xoff(mf * 16 + c16, k << 1));
#pragma unroll
    for (int ef = 0; ef < 2; ++ef)
#pragma unroll
      for (int mf = 0; mf < 4; ++mf)
        acc[ef][mf] = __builtin_amdgcn_mfma_f32_16x16x32_bf16(wa[ks][ef], xb[mf], acc[ef][mf], 0, 0, 0);
  }

#pragma unroll
  for (int ef = 0; ef < 2; ++ef) {
    const int e0 = w * 32 + ef * 16 + (g << 2);
    const float4 b4 = *(const float4*)(bias + e0);
#pragma unroll
    for (int mf = 0; mf < 4; ++mf) {
      const int m = mf * 16 + c16;
      bf16x4_t old = *(const bf16x4_t*)(Xin + xoff(m, e0 << 1));
      bf16x4_t nw;
      nw[0] = (__bf16)(fmaxf(acc[ef][mf][0] + b4.x, 0.f) + (float)old[0]);
      nw[1] = (__bf16)(fmaxf(acc[ef][mf][1] + b4.y, 0.f) + (float)old[1]);
      nw[2] = (__bf16)(fmaxf(acc[ef][mf][2] + b4.z, 0.f) + (float)old[2]);
      nw[3] = (__bf16)(fmaxf(acc[ef][mf][3] + b4.w, 0.f) + (float)old[3]);
      *(bf16x4_t*)(Xout + xoff(m, e0 << 1)) = nw;
    }
  }
  __syncthreads();
}

// ---------------- fused main kernel (async, bf16 images) --------------------
__global__ __launch_bounds__(TPB, 4) void fused_async(
    const unsigned short* __restrict__ fimg, const unsigned short* __restrict__ vimg,
    const float* __restrict__ amask, const float* __restrict__ ftw,
    const unsigned short* __restrict__ WtF, const float* __restrict__ bfb,
    const unsigned short* __restrict__ WtV, const float* __restrict__ bvb,
    const unsigned short* __restrict__ qmb, float* __restrict__ partials) {
  const int bid0 = blockIdx.x;
  const int bid = (bid0 & 7) * 64 + (bid0 >> 3);   // XCD-chunked swizzle (512 % 8 == 0)
  const int b = bid / NT, tb = bid % NT;
  const int tid = threadIdx.x;
  const int lane = tid & 63, w = tid >> 6;
  const int c16 = lane & 15, g = lane >> 4, kb = g << 3;

  __shared__ __align__(128) char X0[TILE_BYTES];          // 32 KB
  __shared__ __align__(128) char X1[TILE_BYTES];          // 32 KB
  __shared__ __align__(16) unsigned short Ws[Q_][FT + 8]; // attn weights [q][f] bf16

  const char* fimgB = (const char*)fimg + (size_t)(b * 64 + tb * CH) * TILE_BYTES;
  const char* vimgB = (const char*)vimg + (size_t)(b * 64 + tb * CH) * TILE_BYTES;

  f32x4 pacc[2];
  pacc[0] = (f32x4){0.f, 0.f, 0.f, 0.f};
  pacc[1] = (f32x4){0.f, 0.f, 0.f, 0.f};

  // prologue: stage features tile 0
  stage_async(X0, fimgB, w, lane);
  __syncthreads();   // drains vmcnt

  for (int c = 0; c < CH; ++c) {
    const int f0 = (tb * CH + c) * FT;

    // ---- f-mapper: X0 -> X1 -> X0 (Fm in X0) ----
    layer_pp(X0, X1, WtF, bfb, w, lane);
    layer_pp(X1, X0, WtF + 65536, bfb + E_, w, lane);

    // ---- issue V-tile loads into X1 (dead after L2's barrier) ----
    stage_async(X1, vimgB + c * TILE_BYTES, w, lane);

    // ---- waves 0-3: S = qm @ Fm^T -> Ws (reads X0 only) ----
    if (w < 4) {
      f32x4 s = (f32x4){0.f, 0.f, 0.f, 0.f};
      const int fl = w * 16 + c16;
      const unsigned short* qbase = qmb + (size_t)(b * Q_ + c16) * E_ + kb;
#pragma unroll
      for (int ks = 0; ks < 8; ++ks) {
        bf16x8_t qa = *(const bf16x8_t*)(qbase + ks * 32);
        bf16x8_t xb = *(const bf16x8_t*)(X0 + xoff(fl, (ks * 32 + kb) << 1));
        s = __builtin_amdgcn_mfma_f32_16x16x32_bf16(qa, xb, s, 0, 0, 0);
      }
      const int fg = f0 + fl;
      const float lw = ftw[b * F_ + fg] * amask[b * F_ + fg];
#pragma unroll
      for (int r = 0; r < 4; ++r) {
        float sg = 1.f / (1.f + __expf(-s[r]));
        Ws[g * 4 + r][fl] = f2bf_bits(sg * lw);
      }
    }
    __syncthreads();   // drains V-tile vmcnt; X1 = values tile, Ws ready

    // ---- v-mapper: X1 -> X0 -> X1 (Vm in X1) ----
    layer_pp(X1, X0, WtV, bvb, w, lane);
    layer_pp(X0, X1, WtV + 65536, bvb + E_, w, lane);

    // ---- issue next chunk's features loads into X0 (dead after VL2) ----
    if (c + 1 < CH) stage_async(X0, fimgB + (c + 1) * TILE_BYTES, w, lane);

    // ---- P += Ws[16,FT] @ Vm[FT,256]; wave w owns e in [w*32, w*32+32) ----
#pragma unroll
    for (int ks = 0; ks < FT / 32; ++ks) {
      bf16x8_t a = *(const bf16x8_t*)&Ws[c16][ks * 32 + kb];
#pragma unroll
      for (int nf = 0; nf < 2; ++nf) {
        const int e = w * 32 + nf * 16 + c16;
        bf16x8_t bb;
#pragma unroll
        for (int i = 0; i < 8; ++i) {
          const int f = ks * 32 + kb + i;
          bb[i] = *(const __bf16*)(X1 + xoff(f, e << 1));
        }
        pacc[nf] = __builtin_amdgcn_mfma_f32_16x16x32_bf16(a, bb, pacc[nf], 0, 0, 0);
      }
    }
    __syncthreads();   // drains next-feat vmcnt; X0 ready for next chunk
  }

  // ---- write pooled partials [b][tb][q][e]; D[q][e]: q = g*4+r ----
#pragma unroll
  for (int nf = 0; nf < 2; ++nf) {
    const int e = w * 32 + nf * 16 + c16;
#pragma unroll
    for (int r = 0; r < 4; ++r) {
      const int q = g * 4 + r;
      partials[(((size_t)b * NT + tb) * Q_ + q) * E_ + e] = pacc[nf][r];
    }
  }
}

// ---------------- fallback: synchronous fused kernel ------------------------
__device__ __forceinline__ void cvt_store(char* Xs, int r, int cb, const float* __restrict__ p) {
  const float4* s4 = (const float4*)p;
  float4 v0 = s4[0], v1 = s4[1];
  bf16x8_t o;
  o[0] = (__bf16)v0.x; o[1] = (__bf16)v0.y; o[2] = (__bf16)v0.z; o[3] = (__bf16)v0.w;
  o[4] = (__bf16)v1.x; o[5] = (__bf16)v1.y; o[6] = (__bf16)v1.z; o[7] = (__bf16)v1.w;
  *(bf16x8_t*)(Xs + xoff(r, cb)) = o;
}
__global__ __launch_bounds__(TPB, 4) void fused_sync(
    const float* __restrict__ features, const float* __restrict__ values,
    const float* __restrict__ amask, const float* __restrict__ ftw,
    const unsigned short* __restrict__ WtF, const float* __restrict__ bfb,
    const unsigned short* __restrict__ WtV, const float* __restrict__ bvb,
    const unsigned short* __restrict__ qmb, float* __restrict__ partials) {
  const int bid0 = blockIdx.x;
  const int bid = (bid0 & 7) * 64 + (bid0 >> 3);
  const int b = bid / NT, tb = bid % NT;
  const int tid = threadIdx.x;
  const int lane = tid & 63, w = tid >> 6;
  const int c16 = lane & 15, g = lane >> 4, kb = g << 3;

  __shared__ __align__(128) char X0[TILE_BYTES];
  __shared__ __align__(128) char X1[TILE_BYTES];
  __shared__ __align__(16) unsigned short Ws[Q_][FT + 8];

  f32x4 pacc[2];
  pacc[0] = (f32x4){0.f, 0.f, 0.f, 0.f};
  pacc[1] = (f32x4){0.f, 0.f, 0.f, 0.f};

  for (int c = 0; c < CH; ++c) {
    const int f0 = (tb * CH + c) * FT;
#pragma unroll
    for (int j = 0; j < 4; ++j) {
      int u = j * 512 + tid;
      cvt_store(X0, u >> 5, (u & 31) << 4,
                features + (size_t)(b * F_ + f0) * E_ + (u >> 5) * E_ + ((u & 31) << 3));
    }
    __syncthreads();
    layer_pp(X0, X1, WtF, bfb, w, lane);
    layer_pp(X1, X0, WtF + 65536, bfb + E_, w, lane);
    if (w < 4) {
      f32x4 s = (f32x4){0.f, 0.f, 0.f, 0.f};
      const int fl = w * 16 + c16;
      const unsigned short* qbase = qmb + (size_t)(b * Q_ + c16) * E_ + kb;
#pragma unroll
      for (int ks = 0; ks < 8; ++ks) {
        bf16x8_t qa = *(const bf16x8_t*)(qbase + ks * 32);
        bf16x8_t xb = *(const bf16x8_t*)(X0 + xoff(fl, (ks * 32 + kb) << 1));
        s = __builtin_amdgcn_mfma_f32_16x16x32_bf16(qa, xb, s, 0, 0, 0);
      }
      const int fg = f0 + fl;
      const float lw = ftw[b * F_ + fg] * amask[b * F_ + fg];
#pragma unroll
      for (int r = 0; r < 4; ++r) {
        float sg = 1.f / (1.f + __expf(-s[r]));
        Ws[g * 4 + r][fl] = f2bf_bits(sg * lw);
      }
    } else {
      const int t4 = tid - 256;
#pragma unroll
      for (int j = 0; j < 8; ++j) {
        int u = j * 256 + t4;
        cvt_store(X1, u >> 5, (u & 31) << 4,
                  values + (size_t)(b * F_ + f0) * E_ + (u >> 5) * E_ + ((u & 31) << 3));
      }
    }
    __syncthreads();
    layer_pp(X1, X0, WtV, bvb, w, lane);
    layer_pp(X0, X1, WtV + 65536, bvb + E_, w, lane);
#pragma unroll
    for (int ks = 0; ks < FT / 32; ++ks) {
      bf16x8_t a = *(const bf16x8_t*)&Ws[c16][ks * 32 + kb];
#pragma unroll
      for (int nf = 0; nf < 2; ++nf) {
        const int e = w * 32 + nf * 16 + c16;
        bf16x8_t bb;
#pragma unroll
        for (int i = 0; i < 8; ++i) {
          const int f = ks * 32 + kb + i;
          bb[i] = *(const __bf16*)(X1 + xoff(f, e << 1));
        }
        pacc[nf] = __builtin_amdgcn_mfma_f32_16x16x32_bf16(a, bb, pacc[nf], 0, 0, 0);
      }
    }
    __syncthreads();
  }
#pragma unroll
  for (int nf = 0; nf < 2; ++nf) {
    const int e = w * 32 + nf * 16 + c16;
#pragma unroll
    for (int r = 0; r < 4; ++r) {
      const int q = g * 4 + r;
      partials[(((size_t)b * NT + tb) * Q_ + q) * E_ + e] = pacc[nf][r];
    }
  }
}

// ---------------- reduce + c-mapper + output projection ---------------------
__global__ __launch_bounds__(256) void tail_kernel(
    const float* __restrict__ partials, const float* __restrict__ WcT,
    const float* __restrict__ bc, const float* __restrict__ Wout,
    const float* __restrict__ bout, float* __restrict__ out) {
  int b = blockIdx.x, t = threadIdx.x;
  __shared__ float xp[Q_][E_ + 1];
  for (int q = 0; q < Q_; ++q) {
    float s = 0.f;
#pragma unroll 4
    for (int tb = 0; tb < NT; ++tb)
      s += partials[(((size_t)(b * NT + tb)) * Q_ + q) * E_ + t];
    xp[q][t] = s;
  }
  __syncthreads();
  for (int l = 0; l < LAY_; ++l) {
    const float* Wrow = WcT + l * E_ * E_ + t * E_;   // row t: contiguous k
    float acc[Q_];
#pragma unroll
    for (int r = 0; r < Q_; ++r) acc[r] = 0.f;
    for (int k = 0; k < E_; k += 4) {
      const float4 wv = *(const float4*)(Wrow + k);
#pragma unroll
      for (int r = 0; r < Q_; ++r)
        acc[r] += xp[r][k] * wv.x + xp[r][k + 1] * wv.y
                + xp[r][k + 2] * wv.z + xp[r][k + 3] * wv.w;
    }
    float be = bc[l * E_ + t];
    __syncthreads();
#pragma unroll
    for (int r = 0; r < Q_; ++r) xp[r][t] = fmaxf(acc[r] + be, 0.f) + xp[r][t];
    __syncthreads();
  }
  if (t < Q_ * NL_) {
    int q = t / NL_, n = t % NL_;
    float s = bout[n];
    for (int k = 0; k < E_; ++k) s += xp[q][k] * Wout[k * NL_ + n];
    out[(b * Q_ + q) * NL_ + n] = s;
  }
}

// ---------------- launch -----------------------------------------------------
extern "C" void kernel_launch(void* const* d_in, const int* in_sizes, int n_in,
                              void* d_out, int out_size, void* d_ws, size_t ws_size,
                              hipStream_t stream) {
  (void)in_sizes; (void)n_in; (void)out_size;
  const float* query    = (const float*)d_in[0];
  const float* features = (const float*)d_in[1];
  const float* values   = (const float*)d_in[2];
  const float* amask    = (const float*)d_in[3];
  const float* ftw      = (const float*)d_in[4];
  const float* Wq       = (const float*)d_in[5];
  const float* bq       = (const float*)d_in[6];
  const float* Wf       = (const float*)d_in[7];
  const float* bfb      = (const float*)d_in[8];
  const float* Wv       = (const float*)d_in[9];
  const float* bvb      = (const float*)d_in[10];
  const float* Wc       = (const float*)d_in[11];
  const float* bcb      = (const float*)d_in[12];
  const float* Wout     = (const float*)d_in[13];
  const float* bout     = (const float*)d_in[14];
  float* out = (float*)d_out;

  char* ws = (char*)d_ws;
  unsigned short* WtF = (unsigned short*)(ws);             // 256 KB
  unsigned short* WtV = (unsigned short*)(ws + 262144);    // 256 KB
  unsigned short* qmb = (unsigned short*)(ws + 524288);    // 256 KB
  float* WcT          = (float*)(ws + 786432);             // 512 KB
  float* partials     = (float*)(ws + 1310720);            // 8.4 MB -> ends 9699328
  unsigned short* fimg = (unsigned short*)(ws + 9699328);  // 64 MB
  unsigned short* vimg = (unsigned short*)(ws + 9699328 + 67108864);  // 64 MB
  const size_t need_async = 9699328 + 2ull * 67108864;

  const bool async_ok = (ws_size >= need_async);
  const int inB = async_ok ? 8192 : 0;

  prep_all_kernel<<<inB + 1536 + B_, 256, 0, stream>>>(
      features, values, fimg, vimg, Wf, Wv, WtF, WtV, Wc, WcT,
      query, Wq, bq, qmb, inB);

  if (async_ok) {
    fused_async<<<B_ * NT, TPB, 0, stream>>>(fimg, vimg, amask, ftw,
                                             WtF, bfb, WtV, bvb, qmb, partials);
  } else {
    fused_sync<<<B_ * NT, TPB, 0, stream>>>(features, values, amask, ftw,
                                            WtF, bfb, WtV, bvb, qmb, partials);
  }
  tail_kernel<<<B_, 256, 0, stream>>>(partials, WcT, bcb, Wout, bout, out);
}